// Round 4
// baseline (1127.038 us; speedup 1.0000x reference)
//
#include <hip/hip_runtime.h>
#include <stdint.h>

typedef unsigned short bfu;
typedef __bf16 bf8v __attribute__((ext_vector_type(8)));
typedef unsigned short us8 __attribute__((ext_vector_type(8)));
typedef unsigned short us4 __attribute__((ext_vector_type(4)));
typedef float f4v __attribute__((ext_vector_type(4)));

__device__ __forceinline__ float bf2f(bfu u) {
    union { unsigned u; float f; } c; c.u = ((unsigned)u) << 16; return c.f;
}
__device__ __forceinline__ bfu f2bf(float f) {
    union { float f; unsigned u; } c; c.f = f;
    unsigned r = c.u + 0x7fffu + ((c.u >> 16) & 1u);
    return (bfu)(r >> 16);
}
__device__ __forceinline__ f4v mfma16(us8 a, us8 b, f4v c) {
    return __builtin_amdgcn_mfma_f32_16x16x32_bf16(
        __builtin_bit_cast(bf8v, a), __builtin_bit_cast(bf8v, b), c, 0, 0, 0);
}

// ---------------------------------------------------------------------------
// GEMM: C[M,N] = A[M,K] (bf16 row-major, K contig) @ Bt[N,K]^T (bf16)
// Reg-staged (issue-early) variant: global loads issue BEFORE the barrier so
// HBM latency overlaps the previous tile's MFMA work. (R1-measured; the
// global_load_lds swap was tried in R2 and was not faster at these grids.)
// EPI 0: bf16 store; 1: f32 out = resF + C; 2: relu->bf16.
// ---------------------------------------------------------------------------
template<int BM, int BN, int EPI>
__global__ __launch_bounds__(256) void gemm_bt(
    const bfu* __restrict__ A, const bfu* __restrict__ Bt,
    const float* __restrict__ resF, void* __restrict__ outP,
    int K, int lda, int ldb, int ldc,
    long long aZs, long long aBs, long long aHs,
    long long bZs, long long bBs, long long bHs,
    long long cZs, long long cBs, long long cHs,
    int bh0)
{
    constexpr int BK = 64;
    constexpr int WM = BM / 2, WN = BN / 2;
    constexpr int TM = WM / 16, TN = WN / 16;
    __shared__ __align__(16) bfu sA[BM * BK];
    __shared__ __align__(16) bfu sB[BN * BK];

    const int tid  = threadIdx.x;
    const int lane = tid & 63;
    const int wid  = tid >> 6;
    const int wr = wid >> 1, wc = wid & 1;

    const int z  = blockIdx.z;
    const int bh = bh0 + z;
    const int bb = bh >> 4, hh = bh & 15;
    const long long aOff = aZs * z + aBs * bb + aHs * hh;
    const long long bOff = bZs * z + bBs * bb + bHs * hh;
    const long long cOff = cZs * z + cBs * bb + cHs * hh;

    const int m0 = blockIdx.y * BM;
    const int n0 = blockIdx.x * BN;

    f4v acc[TM][TN];
    #pragma unroll
    for (int i = 0; i < TM; ++i)
        #pragma unroll
        for (int j = 0; j < TN; ++j)
            acc[i][j] = (f4v)0.0f;

    const bfu* gA = A + aOff + (long long)m0 * lda;
    const bfu* gB = Bt + bOff + (long long)n0 * ldb;
    const int rsub = tid >> 3;        // 0..31
    const int kb   = (tid & 7) * 8;   // bf16 offset within 64-wide K slab

    for (int k0 = 0; k0 < K; k0 += BK) {
        us8 ra[BM / 32], rb[BN / 32];
        #pragma unroll
        for (int it = 0; it < BM / 32; ++it)
            ra[it] = *(const us8*)(gA + (long long)(it * 32 + rsub) * lda + k0 + kb);
        #pragma unroll
        for (int it = 0; it < BN / 32; ++it)
            rb[it] = *(const us8*)(gB + (long long)(it * 32 + rsub) * ldb + k0 + kb);

        __syncthreads();   // prev tile's LDS reads done before overwrite
        #pragma unroll
        for (int it = 0; it < BM / 32; ++it)
            *(us8*)&sA[(it * 32 + rsub) * BK + kb] = ra[it];
        #pragma unroll
        for (int it = 0; it < BN / 32; ++it)
            *(us8*)&sB[(it * 32 + rsub) * BK + kb] = rb[it];
        __syncthreads();

        #pragma unroll
        for (int kk = 0; kk < BK; kk += 32) {
            const int kro = kk + ((lane >> 4) << 3);
            us8 af[TM], bfr[TN];
            #pragma unroll
            for (int i = 0; i < TM; ++i)
                af[i] = *(const us8*)&sA[(wr * WM + i * 16 + (lane & 15)) * BK + kro];
            #pragma unroll
            for (int j = 0; j < TN; ++j)
                bfr[j] = *(const us8*)&sB[(wc * WN + j * 16 + (lane & 15)) * BK + kro];
            #pragma unroll
            for (int i = 0; i < TM; ++i)
                #pragma unroll
                for (int j = 0; j < TN; ++j)
                    acc[i][j] = mfma16(af[i], bfr[j], acc[i][j]);
        }
    }

    const int quad = lane >> 4;
    const int cn = lane & 15;
    #pragma unroll
    for (int i = 0; i < TM; ++i) {
        #pragma unroll
        for (int j = 0; j < TN; ++j) {
            const int col = n0 + wc * WN + j * 16 + cn;
            #pragma unroll
            for (int r = 0; r < 4; ++r) {
                const int row = m0 + wr * WM + i * 16 + quad * 4 + r;
                const long long idx = cOff + (long long)row * ldc + col;
                const float v = acc[i][j][r];
                if constexpr (EPI == 0) ((bfu*)outP)[idx] = f2bf(v);
                else if constexpr (EPI == 1) ((float*)outP)[idx] = resF[idx] + v;
                else ((bfu*)outP)[idx] = f2bf(fmaxf(v, 0.0f));
            }
        }
    }
}

// ---------------------------------------------------------------------------
// Fused cross-attention v5: one block per (bh, 16-row Q-tile).
// Grid is (x=bh, y=q-tile) so flat id = bh + 64*q  =>  XCD = bh % 8 for
// every q-tile: ALL 128 q-blocks of a bh run on ONE XCD. Per-XCD K/V
// residency = 8 bh * 256 KB = 2 MB < 4 MB L2 -> K/V stay L2-hit for the
// whole kernel (R3 measured the old x-fast order as L2-miss/L3-BW-bound:
// ~2.9 GB L2-fill @ ~294 us, insensitive to occupancy/HBM/conflicts).
// Bias sharing survives: bh = 16b + h => bh%8 = h%8, the 4 batches with the
// same h are 16 apart in dispatch order (same XCD, temporally adjacent).
// Bias prefetch in NAMED register arrays (R2's runtime-indexed version went
// to scratch: +524 MB WRITE_SIZE — rule #20). Phase 3: unroll 8, 2 acc chains.
// ---------------------------------------------------------------------------
#define SROW 1036
__global__ __launch_bounds__(256, 4) void xattn(
    const bfu* __restrict__ q2,    // (b, 2048, 1024), head h at col h*64
    const bfu* __restrict__ k2,    // (b, 1024, 1024)
    const bfu* __restrict__ v2t,   // (bh=b*16+h, 64, 1024) = (d, key)
    const float* __restrict__ bias,// (16, 2048, 1024) fp32
    bfu* __restrict__ O)           // (b, 2048, 1024)
{
    __shared__ __align__(16) bfu S[16 * SROW];
    const int tid = threadIdx.x, lane = tid & 63, wid = tid >> 6;
    const int quad = lane >> 4, l16 = lane & 15;
    const int bh = blockIdx.x;                  // x = bh -> XCD = bh % 8
    const int b = bh >> 4, h = bh & 15;
    const int q0 = blockIdx.y * 16;

    // bias prefetch, rows wid*4 + {0,1}: named arrays, constant indices only
    const float* bp = bias + ((long long)h * 2048 + q0 + wid * 4) * 1024 + lane * 16;
    f4v br0[4], br1[4];
    #pragma unroll
    for (int j = 0; j < 4; ++j) br0[j] = *(const f4v*)(bp + j * 4);
    #pragma unroll
    for (int j = 0; j < 4; ++j) br1[j] = *(const f4v*)(bp + 1024 + j * 4);

    // phase 1: all 16 q-rows, keys [wid*256, wid*256+256)
    const int kh0 = wid * 256;
    const bfu* qbase = q2 + ((long long)b * 2048 + q0) * 1024 + h * 64;
    const us8 af0 = *(const us8*)(qbase + (long long)l16 * 1024 + quad * 8);
    const us8 af1 = *(const us8*)(qbase + (long long)l16 * 1024 + 32 + quad * 8);
    const bfu* kbase = k2 + (long long)b * 1048576 + h * 64;
    #pragma unroll 4
    for (int t = 0; t < 16; ++t) {
        const int n0 = kh0 + t * 16;
        const bfu* kr = kbase + (long long)(n0 + l16) * 1024 + quad * 8;
        const us8 bf0 = *(const us8*)kr;
        const us8 bf1 = *(const us8*)(kr + 32);
        f4v acc = (f4v)0.0f;
        acc = mfma16(af0, bf0, acc);
        acc = mfma16(af1, bf1, acc);
        #pragma unroll
        for (int r = 0; r < 4; ++r)
            S[(quad * 4 + r) * SROW + n0 + l16] = f2bf(acc[r]);
    }
    // bias prefetch, rows wid*4 + {2,3}: latency hides under the barrier
    f4v br2[4], br3[4];
    #pragma unroll
    for (int j = 0; j < 4; ++j) br2[j] = *(const f4v*)(bp + 2048 + j * 4);
    #pragma unroll
    for (int j = 0; j < 4; ++j) br3[j] = *(const f4v*)(bp + 3072 + j * 4);
    __syncthreads();

    // phase 2: softmax, 4 rows per wave, fully unrolled; all indices constant
    auto dorow = [&](int row, const f4v bv[4]) {
        bfu* sp = &S[row * SROW + lane * 16];
        const us8 s0 = *(const us8*)sp;
        const us8 s1 = *(const us8*)(sp + 8);
        float v[16];
        #pragma unroll
        for (int j = 0; j < 8; ++j) v[j] = bf2f(s0[j]) + bv[j >> 2][j & 3];
        #pragma unroll
        for (int j = 0; j < 8; ++j) v[8 + j] = bf2f(s1[j]) + bv[2 + (j >> 2)][j & 3];
        float m = v[0];
        #pragma unroll
        for (int j = 1; j < 16; ++j) m = fmaxf(m, v[j]);
        #pragma unroll
        for (int o = 32; o; o >>= 1) m = fmaxf(m, __shfl_xor(m, o));
        float s = 0.f;
        #pragma unroll
        for (int j = 0; j < 16; ++j) { v[j] = __expf(v[j] - m); s += v[j]; }
        #pragma unroll
        for (int o = 32; o; o >>= 1) s += __shfl_xor(s, o);
        const float inv = 1.0f / s;
        us8 o0, o1;
        #pragma unroll
        for (int j = 0; j < 8; ++j) { o0[j] = f2bf(v[j] * inv); o1[j] = f2bf(v[8 + j] * inv); }
        *(us8*)sp = o0;
        *(us8*)(sp + 8) = o1;
    };
    dorow(wid * 4 + 0, br0);
    dorow(wid * 4 + 1, br1);
    dorow(wid * 4 + 2, br2);
    dorow(wid * 4 + 3, br3);
    __syncthreads();

    // phase 3: wave w -> d-cols [w*16, w*16+16), all 16 rows, one 16x16 tile
    // unroll 8, two accumulator chains to break the serial MFMA dependency
    const bfu* vb = v2t + (long long)bh * 65536 + (long long)(wid * 16 + l16) * 1024;
    f4v a0 = (f4v)0.0f, a1 = (f4v)0.0f;
    for (int k0 = 0; k0 < 1024; k0 += 256) {
        us8 pa[8], vf[8];
        #pragma unroll
        for (int j = 0; j < 8; ++j) {
            pa[j] = *(const us8*)&S[l16 * SROW + k0 + j * 32 + quad * 8];
            vf[j] = *(const us8*)(vb + k0 + j * 32 + quad * 8);
        }
        #pragma unroll
        for (int j = 0; j < 8; j += 2) {
            a0 = mfma16(pa[j],     vf[j],     a0);
            a1 = mfma16(pa[j + 1], vf[j + 1], a1);
        }
    }
    const f4v acc3 = a0 + a1;
    bfu* ob = O + ((long long)b * 2048 + q0) * 1024 + h * 64 + wid * 16;
    #pragma unroll
    for (int r = 0; r < 4; ++r)
        ob[(long long)(quad * 4 + r) * 1024 + l16] = f2bf(acc3[r]);
}

// ---------------------------------------------------------------------------
// fp32 -> bf16 elementwise (4 per thread)
// ---------------------------------------------------------------------------
__global__ __launch_bounds__(256) void cvt_f2b(
    const float* __restrict__ in, bfu* __restrict__ out)
{
    const long long i = ((long long)blockIdx.x * 256 + threadIdx.x) * 4;
    f4v v = *(const f4v*)(in + i);
    us4 o;
    #pragma unroll
    for (int k = 0; k < 4; ++k) o[k] = f2bf(v[k]);
    *(us4*)(out + i) = o;
}

// ---------------------------------------------------------------------------
// Transposes. Weight transposes read fp32, write bf16.
// ---------------------------------------------------------------------------
__global__ __launch_bounds__(256) void transpose_plain(
    const float* __restrict__ in, bfu* __restrict__ out, int R, int C)
{
    __shared__ bfu t[32][33];
    const int r0 = blockIdx.y * 32, c0 = blockIdx.x * 32;
    const int tx = threadIdx.x, ty = threadIdx.y;
    #pragma unroll
    for (int i = 0; i < 32; i += 8)
        t[ty + i][tx] = f2bf(in[(long long)(r0 + ty + i) * C + c0 + tx]);
    __syncthreads();
    #pragma unroll
    for (int i = 0; i < 32; i += 8)
        out[(long long)(c0 + ty + i) * R + r0 + tx] = t[tx][ty + i];
}

__global__ __launch_bounds__(256) void transpose_w8(
    const float* p0, const float* p1, const float* p2, const float* p3,
    const float* p4, const float* p5, const float* p6, const float* p7,
    bfu* __restrict__ out)
{
    __shared__ bfu t[32][33];
    const float* srcs[8] = {p0, p1, p2, p3, p4, p5, p6, p7};
    const int zz = blockIdx.z;
    const float* in = srcs[zz];
    bfu* o = out + (long long)zz * 1048576;
    const int r0 = blockIdx.y * 32, c0 = blockIdx.x * 32;
    const int tx = threadIdx.x, ty = threadIdx.y;
    #pragma unroll
    for (int i = 0; i < 32; i += 8)
        t[ty + i][tx] = f2bf(in[(long long)(r0 + ty + i) * 1024 + c0 + tx]);
    __syncthreads();
    #pragma unroll
    for (int i = 0; i < 32; i += 8)
        o[(long long)(c0 + ty + i) * 1024 + r0 + tx] = t[tx][ty + i];
}

// v2 (b,k,h,d) bf16 -> v2t (b,h,d,k) bf16: per (b,h) transpose 1024x64
__global__ __launch_bounds__(256) void transpose_v2(
    const bfu* __restrict__ v2, bfu* __restrict__ v2t)
{
    __shared__ bfu t[32][33];
    const int z = blockIdx.z, b = z >> 4, h = z & 15;
    const bfu* in = v2 + (long long)b * 1048576 + h * 64;
    bfu* o = v2t + (long long)z * 65536;
    const int c0 = blockIdx.x * 32, r0 = blockIdx.y * 32;
    const int tx = threadIdx.x, ty = threadIdx.y;
    #pragma unroll
    for (int i = 0; i < 32; i += 8)
        t[ty + i][tx] = in[(long long)(r0 + ty + i) * 1024 + c0 + tx];
    __syncthreads();
    #pragma unroll
    for (int i = 0; i < 32; i += 8)
        o[(long long)(c0 + ty + i) * 1024 + r0 + tx] = t[tx][ty + i];
}

// ---------------------------------------------------------------------------
// RMSNorm family (fp32 in, bf16 normed out; 256 thr x 4 elems per 1024 row)
// ---------------------------------------------------------------------------
__device__ __forceinline__ float blockSum4(float v, float* red) {
    const int lane = threadIdx.x & 63, wid = threadIdx.x >> 6;
    #pragma unroll
    for (int o = 32; o; o >>= 1) v += __shfl_xor(v, o);
    if (lane == 0) red[wid] = v;
    __syncthreads();
    return red[0] + red[1] + red[2] + red[3];
}

__global__ __launch_bounds__(256) void rmsnorm_f32k(
    const float* __restrict__ X, const float* __restrict__ w, bfu* __restrict__ O)
{
    __shared__ float red[4];
    const long long row = blockIdx.x;
    const int tid = threadIdx.x;
    f4v xv = *(const f4v*)(X + row * 1024 + tid * 4);
    float ss = 0.f;
    #pragma unroll
    for (int i = 0; i < 4; ++i) ss += xv[i] * xv[i];
    ss = blockSum4(ss, red);
    const float sc = rsqrtf(ss * (1.0f / 1024.0f) + 1e-6f);
    f4v wv = *(const f4v*)(w + tid * 4);
    us4 o4;
    #pragma unroll
    for (int i = 0; i < 4; ++i) o4[i] = f2bf(xv[i] * sc * wv[i]);
    *(us4*)(O + row * 1024 + tid * 4) = o4;
}

// x1 = x + attn[b] (fp32); write x1 (fp32) and rmsnorm(x1)*w (bf16)
__global__ __launch_bounds__(256) void add_bcast_rmsnorm(
    const float* __restrict__ X, const float* __restrict__ attn,
    const float* __restrict__ w, float* __restrict__ X1, bfu* __restrict__ O)
{
    __shared__ float red[4];
    const long long row = blockIdx.x;
    const int b = (int)(row >> 11);
    const int tid = threadIdx.x;
    f4v xv = *(const f4v*)(X + row * 1024 + tid * 4);
    f4v av = *(const f4v*)(attn + b * 1024 + tid * 4);
    f4v v;
    float ss = 0.f;
    #pragma unroll
    for (int i = 0; i < 4; ++i) { v[i] = xv[i] + av[i]; ss += v[i] * v[i]; }
    *(f4v*)(X1 + row * 1024 + tid * 4) = v;
    ss = blockSum4(ss, red);
    const float sc = rsqrtf(ss * (1.0f / 1024.0f) + 1e-6f);
    f4v wv = *(const f4v*)(w + tid * 4);
    us4 o4;
    #pragma unroll
    for (int i = 0; i < 4; ++i) o4[i] = f2bf(v[i] * sc * wv[i]);
    *(us4*)(O + row * 1024 + tid * 4) = o4;
}

// ---------------------------------------------------------------------------
// small dense: C[b][n] = dot(A[aBase + b*aStride + :K], Bt[n*K + :K])
// OUTF=0 -> bf16 out; OUTF=1 -> fp32 out
// ---------------------------------------------------------------------------
template<int OUTF>
__global__ __launch_bounds__(256) void vecmat(
    const bfu* __restrict__ A, const bfu* __restrict__ Bt, void* __restrict__ out,
    int K, int N, long long aStride, long long aBase)
{
    __shared__ float sa[1024];
    const int tid = threadIdx.x;
    const int b = blockIdx.y;
    const bfu* ar = A + aBase + (long long)b * aStride;
    for (int k = tid; k < K; k += 256) sa[k] = bf2f(ar[k]);
    __syncthreads();
    const int n = blockIdx.x * 256 + tid;
    if (n < N) {
        const bfu* wr = Bt + (long long)n * K;
        float s = 0.f;
        for (int k = 0; k < K; k += 8) {
            us8 wv = *(const us8*)(wr + k);
            #pragma unroll
            for (int j = 0; j < 8; ++j) s += sa[k + j] * bf2f(wv[j]);
        }
        if constexpr (OUTF) ((float*)out)[(long long)b * N + n] = s;
        else ((bfu*)out)[(long long)b * N + n] = f2bf(s);
    }
}

// ---------------------------------------------------------------------------
// decode self-attention: one block per (b,h); q len = 1, 2048 keys, d=64
// ---------------------------------------------------------------------------
__global__ __launch_bounds__(256) void decode_attn(
    const bfu* __restrict__ qs, const bfu* __restrict__ Kt,
    const bfu* __restrict__ Vt, const float* __restrict__ bias,
    bfu* __restrict__ osmall)
{
    const int bh = blockIdx.x, b = bh >> 4, h = bh & 15;
    const int tid = threadIdx.x, lane = tid & 63, wid = tid >> 6;
    __shared__ float sq[64];
    __shared__ float sc[2048];
    __shared__ float red[4];
    __shared__ float po[4][64];
    if (tid < 64) sq[tid] = bf2f(qs[b * 1024 + h * 64 + tid]);
    __syncthreads();

    const bfu* Kb = Kt + (long long)b * 2048 * 1024 + h * 64;
    float lmax = -1e30f;
    for (int k = tid; k < 2048; k += 256) {
        const us8* kr = (const us8*)(Kb + (long long)k * 1024);
        float s = 0.f;
        #pragma unroll
        for (int j = 0; j < 8; ++j) {
            us8 kv = kr[j];
            #pragma unroll
            for (int t = 0; t < 8; ++t) s += sq[j * 8 + t] * bf2f(kv[t]);
        }
        s += bias[h * 2048 + k];
        sc[k] = s;
        lmax = fmaxf(lmax, s);
    }
    #pragma unroll
    for (int o = 32; o; o >>= 1) lmax = fmaxf(lmax, __shfl_xor(lmax, o));
    if (lane == 0) red[wid] = lmax;
    __syncthreads();
    const float m = fmaxf(fmaxf(red[0], red[1]), fmaxf(red[2], red[3]));
    __syncthreads();

    float lsum = 0.f;
    for (int k = tid; k < 2048; k += 256) {
        const float e = __expf(sc[k] - m);
        sc[k] = e; lsum += e;
    }
    #pragma unroll
    for (int o = 32; o; o >>= 1) lsum += __shfl_xor(lsum, o);
    if (lane == 0) red[wid] = lsum;
    __syncthreads();
    const float S = red[0] + red[1] + red[2] + red[3];

    const bfu* Vb = Vt + (long long)b * 2048 * 1024 + h * 64;
    const int d = tid & 63, ks = tid >> 6;
    float a = 0.f;
    for (int k = ks * 512; k < ks * 512 + 512; ++k)
        a += sc[k] * bf2f(Vb[(long long)k * 1024 + d]);
    po[ks][d] = a;
    __syncthreads();
    if (tid < 64) {
        const float r = (po[0][tid] + po[1][tid] + po[2][tid] + po[3][tid]) / S;
        osmall[b * 1024 + h * 64 + tid] = f2bf(r);
    }
}

// ---------------------------------------------------------------------------
extern "C" void kernel_launch(void* const* d_in, const int* in_sizes, int n_in,
                              void* d_out, int out_size, void* d_ws, size_t ws_size,
                              hipStream_t stream) {
    (void)in_sizes; (void)n_in; (void)out_size; (void)ws_size;
    const float* x     = (const float*)d_in[0];
    const float* enc   = (const float*)d_in[1];
    const float* sbias = (const float*)d_in[2];
    const float* cbias = (const float*)d_in[3];
    const float* wq_s  = (const float*)d_in[4];
    const float* wk_s  = (const float*)d_in[5];
    const float* wv_s  = (const float*)d_in[6];
    const float* wo_s  = (const float*)d_in[7];
    const float* wq_c  = (const float*)d_in[8];
    const float* wk_c  = (const float*)d_in[9];
    const float* wv_c  = (const float*)d_in[10];
    const float* wo_c  = (const float*)d_in[11];
    const float* ff1   = (const float*)d_in[12];
    const float* ff2   = (const float*)d_in[13];
    const float* n1w   = (const float*)d_in[14];
    const float* n2w   = (const float*)d_in[15];
    const float* n3w   = (const float*)d_in[16];
    float* out = (float*)d_out;

    char* ws = (char*)d_ws;
    size_t off = 0;
    auto alloc = [&](size_t bytes) -> void* {
        void* p = (void*)(ws + off);
        off += (bytes + 255) & ~(size_t)255;
        return p;
    };
    bfu*   normed = (bfu*)alloc((size_t)8192 * 1024 * 2);  // normed1/2/3
    bfu*   bufA   = (bfu*)alloc((size_t)8192 * 1024 * 2);  // k_s then q2 / H1 lo
    bfu*   bufB   = (bfu*)alloc((size_t)8192 * 1024 * 2);  // v_s then O  / H1 hi
    bfu*   k2b    = (bfu*)alloc((size_t)4096 * 1024 * 2);
    bfu*   v2b    = (bfu*)alloc((size_t)4096 * 1024 * 2);
    bfu*   v2t    = (bfu*)alloc((size_t)4096 * 1024 * 2);
    bfu*   encb   = (bfu*)alloc((size_t)4096 * 1024 * 2);  // enc cast to bf16
    float* x1f    = (float*)alloc((size_t)8192 * 1024 * 4); // fp32 residual
    bfu*   wT     = (bfu*)alloc((size_t)8 * 1048576 * 2);  // 8 transposed weights
    bfu*   ff1T   = (bfu*)alloc((size_t)4096 * 1024 * 2);
    bfu*   ff2T   = (bfu*)alloc((size_t)4096 * 1024 * 2);
    bfu*   qsb    = (bfu*)alloc(4 * 1024 * 2);
    bfu*   osm    = (bfu*)alloc(4 * 1024 * 2);
    float* attnv  = (float*)alloc(4 * 1024 * 4);
    bfu*   H1     = bufA;  // MLP hidden aliases bufA+bufB (dead by then), 32 MB

    const dim3 tb32(32, 8);

    // input/weight precasts
    cvt_f2b<<<dim3(4096), 256, 0, stream>>>(enc, encb);
    transpose_w8<<<dim3(32, 32, 8), tb32, 0, stream>>>(
        wq_s, wk_s, wv_s, wo_s, wq_c, wk_c, wv_c, wo_c, wT);
    transpose_plain<<<dim3(128, 32, 1), tb32, 0, stream>>>(ff1, ff1T, 1024, 4096);
    transpose_plain<<<dim3(32, 128, 1), tb32, 0, stream>>>(ff2, ff2T, 4096, 1024);

    // norm1
    rmsnorm_f32k<<<dim3(8192), 256, 0, stream>>>(x, n1w, normed);

    // self-attn K/V projections
    gemm_bt<128, 128, 0><<<dim3(8, 64, 1), 256, 0, stream>>>(
        normed, wT + 1 * 1048576, nullptr, bufA, 1024, 1024, 1024, 1024,
        0, 0, 0, 0, 0, 0, 0, 0, 0, 0);
    gemm_bt<128, 128, 0><<<dim3(8, 64, 1), 256, 0, stream>>>(
        normed, wT + 2 * 1048576, nullptr, bufB, 1024, 1024, 1024, 1024,
        0, 0, 0, 0, 0, 0, 0, 0, 0, 0);
    // q = last row per batch
    vecmat<0><<<dim3(4, 4), 256, 0, stream>>>(normed, wT + 0 * 1048576, qsb,
        1024, 1024, (long long)2048 * 1024, (long long)2047 * 1024);
    decode_attn<<<dim3(64), 256, 0, stream>>>(qsb, bufA, bufB, sbias, osm);
    vecmat<1><<<dim3(4, 4), 256, 0, stream>>>(osm, wT + 3 * 1048576, attnv,
        1024, 1024, 1024, 0);
    add_bcast_rmsnorm<<<dim3(8192), 256, 0, stream>>>(x, attnv, n2w, x1f, normed);

    // cross-attn projections
    gemm_bt<128, 128, 0><<<dim3(8, 64, 1), 256, 0, stream>>>(
        normed, wT + 4 * 1048576, nullptr, bufA, 1024, 1024, 1024, 1024,
        0, 0, 0, 0, 0, 0, 0, 0, 0, 0);
    gemm_bt<128, 128, 0><<<dim3(8, 32, 1), 256, 0, stream>>>(
        encb, wT + 5 * 1048576, nullptr, k2b, 1024, 1024, 1024, 1024,
        0, 0, 0, 0, 0, 0, 0, 0, 0, 0);
    gemm_bt<128, 128, 0><<<dim3(8, 32, 1), 256, 0, stream>>>(
        encb, wT + 6 * 1048576, nullptr, v2b, 1024, 1024, 1024, 1024,
        0, 0, 0, 0, 0, 0, 0, 0, 0, 0);
    transpose_v2<<<dim3(2, 32, 64), tb32, 0, stream>>>(v2b, v2t);

    // fused cross-attention (grid x=bh, y=q-tile -> bh pinned to XCD bh%8)
    xattn<<<dim3(64, 128), 256, 0, stream>>>(bufA, k2b, v2t, cbias, bufB);

    // wo_c with residual add: x2 = x1 + O@woT (fp32, in place over x1f)
    gemm_bt<128, 128, 1><<<dim3(8, 64, 1), 256, 0, stream>>>(
        bufB, wT + 7 * 1048576, x1f, x1f, 1024, 1024, 1024, 1024,
        0, 0, 0, 0, 0, 0, 0, 0, 0, 0);

    // norm3 + MLP (M-chunked, hidden aliases bufA+bufB = 32 MB)
    rmsnorm_f32k<<<dim3(8192), 256, 0, stream>>>(x1f, n3w, normed);
    for (int mc = 0; mc < 8192; mc += 4096) {
        gemm_bt<128, 128, 2><<<dim3(32, 32, 1), 256, 0, stream>>>(
            normed + (long long)mc * 1024, ff1T, nullptr, H1,
            1024, 1024, 1024, 4096,
            0, 0, 0, 0, 0, 0, 0, 0, 0, 0);
        gemm_bt<128, 128, 1><<<dim3(8, 32, 1), 256, 0, stream>>>(
            H1, ff2T, x1f + (long long)mc * 1024, out + (long long)mc * 1024,
            4096, 4096, 4096, 1024,
            0, 0, 0, 0, 0, 0, 0, 0, 0, 0);
    }
}

// Round 5
// 1106.298 us; speedup vs baseline: 1.0187x; 1.0187x over previous
//
#include <hip/hip_runtime.h>
#include <stdint.h>

typedef unsigned short bfu;
typedef __bf16 bf8v __attribute__((ext_vector_type(8)));
typedef unsigned short us8 __attribute__((ext_vector_type(8)));
typedef unsigned short us4 __attribute__((ext_vector_type(4)));
typedef float f4v __attribute__((ext_vector_type(4)));

__device__ __forceinline__ float bf2f(bfu u) {
    union { unsigned u; float f; } c; c.u = ((unsigned)u) << 16; return c.f;
}
__device__ __forceinline__ bfu f2bf(float f) {
    union { float f; unsigned u; } c; c.f = f;
    unsigned r = c.u + 0x7fffu + ((c.u >> 16) & 1u);
    return (bfu)(r >> 16);
}
__device__ __forceinline__ f4v mfma16(us8 a, us8 b, f4v c) {
    return __builtin_amdgcn_mfma_f32_16x16x32_bf16(
        __builtin_bit_cast(bf8v, a), __builtin_bit_cast(bf8v, b), c, 0, 0, 0);
}

// ---------------------------------------------------------------------------
// GEMM: C[M,N] = A[M,K] (bf16 row-major, K contig) @ Bt[N,K]^T (bf16)
// Reg-staged (issue-early). BN=64 instantiations serve N=1024 outputs with a
// 2x bigger grid (4 blocks/CU instead of 2) — R4 showed these launches were
// grid-starved (~293 TF avg, m102 small-N regime).
// EPI 0: bf16 store; 1: f32 out = resF + C; 2: relu->bf16.
// ---------------------------------------------------------------------------
template<int BM, int BN, int EPI>
__global__ __launch_bounds__(256) void gemm_bt(
    const bfu* __restrict__ A, const bfu* __restrict__ Bt,
    const float* __restrict__ resF, void* __restrict__ outP,
    int K, int lda, int ldb, int ldc)
{
    constexpr int BK = 64;
    constexpr int WM = BM / 2, WN = BN / 2;
    constexpr int TM = WM / 16, TN = WN / 16;
    __shared__ __align__(16) bfu sA[BM * BK];
    __shared__ __align__(16) bfu sB[BN * BK];

    const int tid  = threadIdx.x;
    const int lane = tid & 63;
    const int wid  = tid >> 6;
    const int wr = wid >> 1, wc = wid & 1;

    const int m0 = blockIdx.y * BM;
    const int n0 = blockIdx.x * BN;

    f4v acc[TM][TN];
    #pragma unroll
    for (int i = 0; i < TM; ++i)
        #pragma unroll
        for (int j = 0; j < TN; ++j)
            acc[i][j] = (f4v)0.0f;

    const bfu* gA = A + (long long)m0 * lda;
    const bfu* gB = Bt + (long long)n0 * ldb;
    const int rsub = tid >> 3;        // 0..31
    const int kb   = (tid & 7) * 8;   // bf16 offset within 64-wide K slab

    for (int k0 = 0; k0 < K; k0 += BK) {
        us8 ra[BM / 32], rb[BN / 32];
        #pragma unroll
        for (int it = 0; it < BM / 32; ++it)
            ra[it] = *(const us8*)(gA + (long long)(it * 32 + rsub) * lda + k0 + kb);
        #pragma unroll
        for (int it = 0; it < BN / 32; ++it)
            rb[it] = *(const us8*)(gB + (long long)(it * 32 + rsub) * ldb + k0 + kb);

        __syncthreads();   // prev tile's LDS reads done before overwrite
        #pragma unroll
        for (int it = 0; it < BM / 32; ++it)
            *(us8*)&sA[(it * 32 + rsub) * BK + kb] = ra[it];
        #pragma unroll
        for (int it = 0; it < BN / 32; ++it)
            *(us8*)&sB[(it * 32 + rsub) * BK + kb] = rb[it];
        __syncthreads();

        #pragma unroll
        for (int kk = 0; kk < BK; kk += 32) {
            const int kro = kk + ((lane >> 4) << 3);
            us8 af[TM], bfr[TN];
            #pragma unroll
            for (int i = 0; i < TM; ++i)
                af[i] = *(const us8*)&sA[(wr * WM + i * 16 + (lane & 15)) * BK + kro];
            #pragma unroll
            for (int j = 0; j < TN; ++j)
                bfr[j] = *(const us8*)&sB[(wc * WN + j * 16 + (lane & 15)) * BK + kro];
            #pragma unroll
            for (int i = 0; i < TM; ++i)
                #pragma unroll
                for (int j = 0; j < TN; ++j)
                    acc[i][j] = mfma16(af[i], bfr[j], acc[i][j]);
        }
    }

    const int quad = lane >> 4;
    const int cn = lane & 15;
    #pragma unroll
    for (int i = 0; i < TM; ++i) {
        #pragma unroll
        for (int j = 0; j < TN; ++j) {
            const int col = n0 + wc * WN + j * 16 + cn;
            #pragma unroll
            for (int r = 0; r < 4; ++r) {
                const int row = m0 + wr * WM + i * 16 + quad * 4 + r;
                const long long idx = (long long)row * ldc + col;
                const float v = acc[i][j][r];
                if constexpr (EPI == 0) ((bfu*)outP)[idx] = f2bf(v);
                else if constexpr (EPI == 1) ((float*)outP)[idx] = resF[idx] + v;
                else ((bfu*)outP)[idx] = f2bf(fmaxf(v, 0.0f));
            }
        }
    }
}

// ---------------------------------------------------------------------------
// Fused cross-attention v5 (R4 structure, K now read from interleaved KV
// buffer with row stride 2048). Grid (x=bh, y=q-tile): XCD = bh % 8 pins all
// q-tiles of a bh to one XCD (K/V L2-resident, bias L2-shared across b).
// Bias prefetch in NAMED register arrays (rule #20). Phase 3: unroll 8,
// two acc chains.
// ---------------------------------------------------------------------------
#define SROW 1036
__global__ __launch_bounds__(256, 4) void xattn(
    const bfu* __restrict__ q2,    // (b, 2048, 1024), head h at col h*64
    const bfu* __restrict__ kv2,   // (b, 1024, 2048): K cols 0-1023, V 1024-2047
    const bfu* __restrict__ v2t,   // (bh=b*16+h, 64, 1024) = (d, key)
    const float* __restrict__ bias,// (16, 2048, 1024) fp32
    bfu* __restrict__ O)           // (b, 2048, 1024)
{
    __shared__ __align__(16) bfu S[16 * SROW];
    const int tid = threadIdx.x, lane = tid & 63, wid = tid >> 6;
    const int quad = lane >> 4, l16 = lane & 15;
    const int bh = blockIdx.x;                  // x = bh -> XCD = bh % 8
    const int b = bh >> 4, h = bh & 15;
    const int q0 = blockIdx.y * 16;

    // bias prefetch, rows wid*4 + {0,1}: named arrays, constant indices only
    const float* bp = bias + ((long long)h * 2048 + q0 + wid * 4) * 1024 + lane * 16;
    f4v br0[4], br1[4];
    #pragma unroll
    for (int j = 0; j < 4; ++j) br0[j] = *(const f4v*)(bp + j * 4);
    #pragma unroll
    for (int j = 0; j < 4; ++j) br1[j] = *(const f4v*)(bp + 1024 + j * 4);

    // phase 1: all 16 q-rows, keys [wid*256, wid*256+256)
    const int kh0 = wid * 256;
    const bfu* qbase = q2 + ((long long)b * 2048 + q0) * 1024 + h * 64;
    const us8 af0 = *(const us8*)(qbase + (long long)l16 * 1024 + quad * 8);
    const us8 af1 = *(const us8*)(qbase + (long long)l16 * 1024 + 32 + quad * 8);
    const bfu* kbase = kv2 + (long long)b * 2097152 + h * 64;   // row stride 2048
    #pragma unroll 4
    for (int t = 0; t < 16; ++t) {
        const int n0 = kh0 + t * 16;
        const bfu* kr = kbase + (long long)(n0 + l16) * 2048 + quad * 8;
        const us8 bf0 = *(const us8*)kr;
        const us8 bf1 = *(const us8*)(kr + 32);
        f4v acc = (f4v)0.0f;
        acc = mfma16(af0, bf0, acc);
        acc = mfma16(af1, bf1, acc);
        #pragma unroll
        for (int r = 0; r < 4; ++r)
            S[(quad * 4 + r) * SROW + n0 + l16] = f2bf(acc[r]);
    }
    // bias prefetch, rows wid*4 + {2,3}: latency hides under the barrier
    f4v br2[4], br3[4];
    #pragma unroll
    for (int j = 0; j < 4; ++j) br2[j] = *(const f4v*)(bp + 2048 + j * 4);
    #pragma unroll
    for (int j = 0; j < 4; ++j) br3[j] = *(const f4v*)(bp + 3072 + j * 4);
    __syncthreads();

    // phase 2: softmax, 4 rows per wave, fully unrolled; all indices constant
    auto dorow = [&](int row, const f4v bv[4]) {
        bfu* sp = &S[row * SROW + lane * 16];
        const us8 s0 = *(const us8*)sp;
        const us8 s1 = *(const us8*)(sp + 8);
        float v[16];
        #pragma unroll
        for (int j = 0; j < 8; ++j) v[j] = bf2f(s0[j]) + bv[j >> 2][j & 3];
        #pragma unroll
        for (int j = 0; j < 8; ++j) v[8 + j] = bf2f(s1[j]) + bv[2 + (j >> 2)][j & 3];
        float m = v[0];
        #pragma unroll
        for (int j = 1; j < 16; ++j) m = fmaxf(m, v[j]);
        #pragma unroll
        for (int o = 32; o; o >>= 1) m = fmaxf(m, __shfl_xor(m, o));
        float s = 0.f;
        #pragma unroll
        for (int j = 0; j < 16; ++j) { v[j] = __expf(v[j] - m); s += v[j]; }
        #pragma unroll
        for (int o = 32; o; o >>= 1) s += __shfl_xor(s, o);
        const float inv = 1.0f / s;
        us8 o0, o1;
        #pragma unroll
        for (int j = 0; j < 8; ++j) { o0[j] = f2bf(v[j] * inv); o1[j] = f2bf(v[8 + j] * inv); }
        *(us8*)sp = o0;
        *(us8*)(sp + 8) = o1;
    };
    dorow(wid * 4 + 0, br0);
    dorow(wid * 4 + 1, br1);
    dorow(wid * 4 + 2, br2);
    dorow(wid * 4 + 3, br3);
    __syncthreads();

    // phase 3: wave w -> d-cols [w*16, w*16+16), all 16 rows, one 16x16 tile
    // unroll 8, two accumulator chains to break the serial MFMA dependency
    const bfu* vb = v2t + (long long)bh * 65536 + (long long)(wid * 16 + l16) * 1024;
    f4v a0 = (f4v)0.0f, a1 = (f4v)0.0f;
    for (int k0 = 0; k0 < 1024; k0 += 256) {
        us8 pa[8], vf[8];
        #pragma unroll
        for (int j = 0; j < 8; ++j) {
            pa[j] = *(const us8*)&S[l16 * SROW + k0 + j * 32 + quad * 8];
            vf[j] = *(const us8*)(vb + k0 + j * 32 + quad * 8);
        }
        #pragma unroll
        for (int j = 0; j < 8; j += 2) {
            a0 = mfma16(pa[j],     vf[j],     a0);
            a1 = mfma16(pa[j + 1], vf[j + 1], a1);
        }
    }
    const f4v acc3 = a0 + a1;
    bfu* ob = O + ((long long)b * 2048 + q0) * 1024 + h * 64 + wid * 16;
    #pragma unroll
    for (int r = 0; r < 4; ++r)
        ob[(long long)(quad * 4 + r) * 1024 + l16] = f2bf(acc3[r]);
}

// ---------------------------------------------------------------------------
// fp32 -> bf16 elementwise (4 per thread)
// ---------------------------------------------------------------------------
__global__ __launch_bounds__(256) void cvt_f2b(
    const float* __restrict__ in, bfu* __restrict__ out)
{
    const long long i = ((long long)blockIdx.x * 256 + threadIdx.x) * 4;
    f4v v = *(const f4v*)(in + i);
    us4 o;
    #pragma unroll
    for (int k = 0; k < 4; ++k) o[k] = f2bf(v[k]);
    *(us4*)(out + i) = o;
}

// ---------------------------------------------------------------------------
// Transposes. Weight transposes read fp32, write bf16.
// ---------------------------------------------------------------------------
__global__ __launch_bounds__(256) void transpose_plain(
    const float* __restrict__ in, bfu* __restrict__ out, int R, int C)
{
    __shared__ bfu t[32][33];
    const int r0 = blockIdx.y * 32, c0 = blockIdx.x * 32;
    const int tx = threadIdx.x, ty = threadIdx.y;
    #pragma unroll
    for (int i = 0; i < 32; i += 8)
        t[ty + i][tx] = f2bf(in[(long long)(r0 + ty + i) * C + c0 + tx]);
    __syncthreads();
    #pragma unroll
    for (int i = 0; i < 32; i += 8)
        out[(long long)(c0 + ty + i) * R + r0 + tx] = t[tx][ty + i];
}

__global__ __launch_bounds__(256) void transpose_w8(
    const float* p0, const float* p1, const float* p2, const float* p3,
    const float* p4, const float* p5, const float* p6, const float* p7,
    bfu* __restrict__ out)
{
    __shared__ bfu t[32][33];
    const float* srcs[8] = {p0, p1, p2, p3, p4, p5, p6, p7};
    const int zz = blockIdx.z;
    const float* in = srcs[zz];
    bfu* o = out + (long long)zz * 1048576;
    const int r0 = blockIdx.y * 32, c0 = blockIdx.x * 32;
    const int tx = threadIdx.x, ty = threadIdx.y;
    #pragma unroll
    for (int i = 0; i < 32; i += 8)
        t[ty + i][tx] = f2bf(in[(long long)(r0 + ty + i) * 1024 + c0 + tx]);
    __syncthreads();
    #pragma unroll
    for (int i = 0; i < 32; i += 8)
        o[(long long)(c0 + ty + i) * 1024 + r0 + tx] = t[tx][ty + i];
}

// kv2 (b, 1024 keys, 2048) V half (cols 1024+h*64 .. +64) -> v2t (bh, 64, 1024)
__global__ __launch_bounds__(256) void transpose_v2(
    const bfu* __restrict__ kv2, bfu* __restrict__ v2t)
{
    __shared__ bfu t[32][33];
    const int z = blockIdx.z, b = z >> 4, h = z & 15;
    const bfu* in = kv2 + (long long)b * 2097152 + 1024 + h * 64;  // row stride 2048
    bfu* o = v2t + (long long)z * 65536;
    const int c0 = blockIdx.x * 32, r0 = blockIdx.y * 32;
    const int tx = threadIdx.x, ty = threadIdx.y;
    #pragma unroll
    for (int i = 0; i < 32; i += 8)
        t[ty + i][tx] = in[(long long)(r0 + ty + i) * 2048 + c0 + tx];
    __syncthreads();
    #pragma unroll
    for (int i = 0; i < 32; i += 8)
        o[(long long)(c0 + ty + i) * 1024 + r0 + tx] = t[tx][ty + i];
}

// ---------------------------------------------------------------------------
// RMSNorm family (fp32 in, bf16 normed out; 256 thr x 4 elems per 1024 row)
// ---------------------------------------------------------------------------
__device__ __forceinline__ float blockSum4(float v, float* red) {
    const int lane = threadIdx.x & 63, wid = threadIdx.x >> 6;
    #pragma unroll
    for (int o = 32; o; o >>= 1) v += __shfl_xor(v, o);
    if (lane == 0) red[wid] = v;
    __syncthreads();
    return red[0] + red[1] + red[2] + red[3];
}

__global__ __launch_bounds__(256) void rmsnorm_f32k(
    const float* __restrict__ X, const float* __restrict__ w, bfu* __restrict__ O)
{
    __shared__ float red[4];
    const long long row = blockIdx.x;
    const int tid = threadIdx.x;
    f4v xv = *(const f4v*)(X + row * 1024 + tid * 4);
    float ss = 0.f;
    #pragma unroll
    for (int i = 0; i < 4; ++i) ss += xv[i] * xv[i];
    ss = blockSum4(ss, red);
    const float sc = rsqrtf(ss * (1.0f / 1024.0f) + 1e-6f);
    f4v wv = *(const f4v*)(w + tid * 4);
    us4 o4;
    #pragma unroll
    for (int i = 0; i < 4; ++i) o4[i] = f2bf(xv[i] * sc * wv[i]);
    *(us4*)(O + row * 1024 + tid * 4) = o4;
}

// x1 = x + attn[b] (fp32); write x1 (fp32) and rmsnorm(x1)*w (bf16)
__global__ __launch_bounds__(256) void add_bcast_rmsnorm(
    const float* __restrict__ X, const float* __restrict__ attn,
    const float* __restrict__ w, float* __restrict__ X1, bfu* __restrict__ O)
{
    __shared__ float red[4];
    const long long row = blockIdx.x;
    const int b = (int)(row >> 11);
    const int tid = threadIdx.x;
    f4v xv = *(const f4v*)(X + row * 1024 + tid * 4);
    f4v av = *(const f4v*)(attn + b * 1024 + tid * 4);
    f4v v;
    float ss = 0.f;
    #pragma unroll
    for (int i = 0; i < 4; ++i) { v[i] = xv[i] + av[i]; ss += v[i] * v[i]; }
    *(f4v*)(X1 + row * 1024 + tid * 4) = v;
    ss = blockSum4(ss, red);
    const float sc = rsqrtf(ss * (1.0f / 1024.0f) + 1e-6f);
    f4v wv = *(const f4v*)(w + tid * 4);
    us4 o4;
    #pragma unroll
    for (int i = 0; i < 4; ++i) o4[i] = f2bf(v[i] * sc * wv[i]);
    *(us4*)(O + row * 1024 + tid * 4) = o4;
}

// ---------------------------------------------------------------------------
// small dense: C[b][n] = dot(A[aBase + b*aStride + :K], Bt[n*K + :K])
// OUTF=0 -> bf16 out; OUTF=1 -> fp32 out
// ---------------------------------------------------------------------------
template<int OUTF>
__global__ __launch_bounds__(256) void vecmat(
    const bfu* __restrict__ A, const bfu* __restrict__ Bt, void* __restrict__ out,
    int K, int N, long long aStride, long long aBase)
{
    __shared__ float sa[1024];
    const int tid = threadIdx.x;
    const int b = blockIdx.y;
    const bfu* ar = A + aBase + (long long)b * aStride;
    for (int k = tid; k < K; k += 256) sa[k] = bf2f(ar[k]);
    __syncthreads();
    const int n = blockIdx.x * 256 + tid;
    if (n < N) {
        const bfu* wr = Bt + (long long)n * K;
        float s = 0.f;
        for (int k = 0; k < K; k += 8) {
            us8 wv = *(const us8*)(wr + k);
            #pragma unroll
            for (int j = 0; j < 8; ++j) s += sa[k + j] * bf2f(wv[j]);
        }
        if constexpr (OUTF) ((float*)out)[(long long)b * N + n] = s;
        else ((bfu*)out)[(long long)b * N + n] = f2bf(s);
    }
}

// ---------------------------------------------------------------------------
// decode self-attention: one block per (b,h); q len = 1, 2048 keys, d=64.
// KV interleaved: row stride 2048, K at cols 0-1023, V at cols 1024-2047.
// ---------------------------------------------------------------------------
__global__ __launch_bounds__(256) void decode_attn(
    const bfu* __restrict__ qs, const bfu* __restrict__ KV,
    const float* __restrict__ bias, bfu* __restrict__ osmall)
{
    const int bh = blockIdx.x, b = bh >> 4, h = bh & 15;
    const int tid = threadIdx.x, lane = tid & 63, wid = tid >> 6;
    __shared__ float sq[64];
    __shared__ float sc[2048];
    __shared__ float red[4];
    __shared__ float po[4][64];
    if (tid < 64) sq[tid] = bf2f(qs[b * 1024 + h * 64 + tid]);
    __syncthreads();

    const bfu* Kb = KV + (long long)b * 2048 * 2048 + h * 64;
    float lmax = -1e30f;
    for (int k = tid; k < 2048; k += 256) {
        const us8* kr = (const us8*)(Kb + (long long)k * 2048);
        float s = 0.f;
        #pragma unroll
        for (int j = 0; j < 8; ++j) {
            us8 kv = kr[j];
            #pragma unroll
            for (int t = 0; t < 8; ++t) s += sq[j * 8 + t] * bf2f(kv[t]);
        }
        s += bias[h * 2048 + k];
        sc[k] = s;
        lmax = fmaxf(lmax, s);
    }
    #pragma unroll
    for (int o = 32; o; o >>= 1) lmax = fmaxf(lmax, __shfl_xor(lmax, o));
    if (lane == 0) red[wid] = lmax;
    __syncthreads();
    const float m = fmaxf(fmaxf(red[0], red[1]), fmaxf(red[2], red[3]));
    __syncthreads();

    float lsum = 0.f;
    for (int k = tid; k < 2048; k += 256) {
        const float e = __expf(sc[k] - m);
        sc[k] = e; lsum += e;
    }
    #pragma unroll
    for (int o = 32; o; o >>= 1) lsum += __shfl_xor(lsum, o);
    if (lane == 0) red[wid] = lsum;
    __syncthreads();
    const float S = red[0] + red[1] + red[2] + red[3];

    const bfu* Vb = KV + (long long)b * 2048 * 2048 + 1024 + h * 64;
    const int d = tid & 63, ks = tid >> 6;
    float a = 0.f;
    for (int k = ks * 512; k < ks * 512 + 512; ++k)
        a += sc[k] * bf2f(Vb[(long long)k * 2048 + d]);
    po[ks][d] = a;
    __syncthreads();
    if (tid < 64) {
        const float r = (po[0][tid] + po[1][tid] + po[2][tid] + po[3][tid]) / S;
        osmall[b * 1024 + h * 64 + tid] = f2bf(r);
    }
}

// ---------------------------------------------------------------------------
extern "C" void kernel_launch(void* const* d_in, const int* in_sizes, int n_in,
                              void* d_out, int out_size, void* d_ws, size_t ws_size,
                              hipStream_t stream) {
    (void)in_sizes; (void)n_in; (void)out_size; (void)ws_size;
    const float* x     = (const float*)d_in[0];
    const float* enc   = (const float*)d_in[1];
    const float* sbias = (const float*)d_in[2];
    const float* cbias = (const float*)d_in[3];
    const float* wq_s  = (const float*)d_in[4];
    const float* wk_s  = (const float*)d_in[5];
    const float* wv_s  = (const float*)d_in[6];
    const float* wo_s  = (const float*)d_in[7];
    const float* wq_c  = (const float*)d_in[8];
    const float* wk_c  = (const float*)d_in[9];
    const float* wv_c  = (const float*)d_in[10];
    const float* wo_c  = (const float*)d_in[11];
    const float* ff1   = (const float*)d_in[12];
    const float* ff2   = (const float*)d_in[13];
    const float* n1w   = (const float*)d_in[14];
    const float* n2w   = (const float*)d_in[15];
    const float* n3w   = (const float*)d_in[16];
    float* out = (float*)d_out;

    char* ws = (char*)d_ws;
    size_t off = 0;
    auto alloc = [&](size_t bytes) -> void* {
        void* p = (void*)(ws + off);
        off += (bytes + 255) & ~(size_t)255;
        return p;
    };
    // Layout (144 MB + small, same total as R4):
    bfu*   normed = (bfu*)alloc((size_t)8192 * 1024 * 2);   // [0:16)  normed1/2/3
    bfu*   kvs    = (bfu*)alloc((size_t)8192 * 2048 * 2);   // [16:48) self KV interleaved
    bfu*   obuf   = (bfu*)alloc((size_t)8192 * 1024 * 2);   // [48:64) cross-attn O
    bfu*   v2t    = (bfu*)alloc((size_t)4096 * 1024 * 2);   // [64:72)
    bfu*   encb   = (bfu*)alloc((size_t)4096 * 1024 * 2);   // [72:80)
    float* x1f    = (float*)alloc((size_t)8192 * 1024 * 4); // [80:112) fp32 residual
    bfu*   wT     = (bfu*)alloc((size_t)8 * 1048576 * 2);   // [112:128) transposed weights
    bfu*   ff1T   = (bfu*)alloc((size_t)4096 * 1024 * 2);   // [128:136)
    bfu*   ff2T   = (bfu*)alloc((size_t)4096 * 1024 * 2);   // [136:144)
    bfu*   qsb    = (bfu*)alloc(4 * 1024 * 2);
    bfu*   osm    = (bfu*)alloc(4 * 1024 * 2);
    float* attnv  = (float*)alloc(4 * 1024 * 4);
    // Aliases (liveness-checked):
    bfu*   q2b = kvs;                 // cross Q: kvs[0:16) — kvs dead after decode_attn
    bfu*   kv2 = kvs + (size_t)8192 * 1024;  // cross KV interleaved: kvs[16:32)
    bfu*   H1  = kvs;                 // MLP hidden: [16:80) = kvs+obuf+v2t+encb, 64 MB

    const dim3 tb32(32, 8);

    // input/weight precasts
    cvt_f2b<<<dim3(4096), 256, 0, stream>>>(enc, encb);
    transpose_w8<<<dim3(32, 32, 8), tb32, 0, stream>>>(
        wq_s, wk_s, wv_s, wo_s, wq_c, wk_c, wv_c, wo_c, wT);
    transpose_plain<<<dim3(128, 32, 1), tb32, 0, stream>>>(ff1, ff1T, 1024, 4096);
    transpose_plain<<<dim3(32, 128, 1), tb32, 0, stream>>>(ff2, ff2T, 4096, 1024);

    // norm1
    rmsnorm_f32k<<<dim3(8192), 256, 0, stream>>>(x, n1w, normed);

    // self-attn K|V fused projection: normed @ [wk_s|wv_s] -> kvs (ldc 2048)
    gemm_bt<128, 128, 0><<<dim3(16, 64), 256, 0, stream>>>(
        normed, wT + 1 * 1048576, nullptr, kvs, 1024, 1024, 1024, 2048);
    // q = last row per batch
    vecmat<0><<<dim3(4, 4), 256, 0, stream>>>(normed, wT + 0 * 1048576, qsb,
        1024, 1024, (long long)2048 * 1024, (long long)2047 * 1024);
    decode_attn<<<dim3(64), 256, 0, stream>>>(qsb, kvs, sbias, osm);
    vecmat<1><<<dim3(4, 4), 256, 0, stream>>>(osm, wT + 3 * 1048576, attnv,
        1024, 1024, 1024, 0);
    add_bcast_rmsnorm<<<dim3(8192), 256, 0, stream>>>(x, attnv, n2w, x1f, normed);

    // cross-attn projections (kvs dead now; q2b/kv2 alias it)
    gemm_bt<128, 64, 0><<<dim3(16, 64), 256, 0, stream>>>(
        normed, wT + 4 * 1048576, nullptr, q2b, 1024, 1024, 1024, 1024);
    gemm_bt<128, 64, 0><<<dim3(32, 32), 256, 0, stream>>>(
        encb, wT + 5 * 1048576, nullptr, kv2, 1024, 1024, 1024, 2048);
    transpose_v2<<<dim3(2, 32, 64), tb32, 0, stream>>>(kv2, v2t);

    // fused cross-attention (grid x=bh, y=q-tile -> bh pinned to XCD bh%8)
    xattn<<<dim3(64, 128), 256, 0, stream>>>(q2b, kv2, v2t, cbias, obuf);

    // wo_c with residual add: x2 = x1 + O@woT (fp32, in place over x1f)
    gemm_bt<128, 64, 1><<<dim3(16, 64), 256, 0, stream>>>(
        obuf, wT + 7 * 1048576, x1f, x1f, 1024, 1024, 1024, 1024);

    // norm3 + MLP, single full-M launches (H1 = 64 MB dead region)
    rmsnorm_f32k<<<dim3(8192), 256, 0, stream>>>(x1f, n3w, normed);
    gemm_bt<128, 128, 2><<<dim3(32, 64), 256, 0, stream>>>(
        normed, ff1T, nullptr, H1, 1024, 1024, 1024, 4096);
    gemm_bt<128, 64, 1><<<dim3(16, 64), 256, 0, stream>>>(
        H1, ff2T, x1f, out, 4096, 4096, 4096, 1024);
}

// Round 6
// 1040.369 us; speedup vs baseline: 1.0833x; 1.0634x over previous
//
#include <hip/hip_runtime.h>
#include <stdint.h>

typedef unsigned short bfu;
typedef __bf16 bf8v __attribute__((ext_vector_type(8)));
typedef unsigned short us8 __attribute__((ext_vector_type(8)));
typedef unsigned short us4 __attribute__((ext_vector_type(4)));
typedef float f4v __attribute__((ext_vector_type(4)));
typedef float f16v __attribute__((ext_vector_type(16)));

__device__ __forceinline__ float bf2f(bfu u) {
    union { unsigned u; float f; } c; c.u = ((unsigned)u) << 16; return c.f;
}
__device__ __forceinline__ bfu f2bf(float f) {
    union { float f; unsigned u; } c; c.f = f;
    unsigned r = c.u + 0x7fffu + ((c.u >> 16) & 1u);
    return (bfu)(r >> 16);
}
__device__ __forceinline__ f4v mfma16(us8 a, us8 b, f4v c) {
    return __builtin_amdgcn_mfma_f32_16x16x32_bf16(
        __builtin_bit_cast(bf8v, a), __builtin_bit_cast(bf8v, b), c, 0, 0, 0);
}
__device__ __forceinline__ f16v mfma32(us8 a, us8 b, f16v c) {
    return __builtin_amdgcn_mfma_f32_32x32x16_bf16(
        __builtin_bit_cast(bf8v, a), __builtin_bit_cast(bf8v, b), c, 0, 0, 0);
}
// pack two f32 -> one u32 of 2 bf16 (RNE), lo in low16
__device__ __forceinline__ unsigned cvtpk(float lo, float hi) {
    unsigned r;
    asm("v_cvt_pk_bf16_f32 %0, %1, %2" : "=v"(r) : "v"(lo), "v"(hi));
    return r;
}
__device__ __forceinline__ us8 mkfrag(unsigned w0, unsigned w1, unsigned w2, unsigned w3) {
    union { unsigned w[4]; us8 v; } u;
    u.w[0] = w0; u.w[1] = w1; u.w[2] = w2; u.w[3] = w3;
    return u.v;
}

// ---------------------------------------------------------------------------
// GEMM: C[M,N] = A[M,K] (bf16 row-major, K contig) @ Bt[N,K]^T (bf16)
// Reg-staged (issue-early). EPI 0: bf16; 1: f32 = resF + C; 2: relu->bf16.
// ---------------------------------------------------------------------------
template<int BM, int BN, int EPI>
__global__ __launch_bounds__(256) void gemm_bt(
    const bfu* __restrict__ A, const bfu* __restrict__ Bt,
    const float* __restrict__ resF, void* __restrict__ outP,
    int K, int lda, int ldb, int ldc)
{
    constexpr int BK = 64;
    constexpr int WM = BM / 2, WN = BN / 2;
    constexpr int TM = WM / 16, TN = WN / 16;
    __shared__ __align__(16) bfu sA[BM * BK];
    __shared__ __align__(16) bfu sB[BN * BK];

    const int tid  = threadIdx.x;
    const int lane = tid & 63;
    const int wid  = tid >> 6;
    const int wr = wid >> 1, wc = wid & 1;

    const int m0 = blockIdx.y * BM;
    const int n0 = blockIdx.x * BN;

    f4v acc[TM][TN];
    #pragma unroll
    for (int i = 0; i < TM; ++i)
        #pragma unroll
        for (int j = 0; j < TN; ++j)
            acc[i][j] = (f4v)0.0f;

    const bfu* gA = A + (long long)m0 * lda;
    const bfu* gB = Bt + (long long)n0 * ldb;
    const int rsub = tid >> 3;        // 0..31
    const int kb   = (tid & 7) * 8;   // bf16 offset within 64-wide K slab

    for (int k0 = 0; k0 < K; k0 += BK) {
        us8 ra[BM / 32], rb[BN / 32];
        #pragma unroll
        for (int it = 0; it < BM / 32; ++it)
            ra[it] = *(const us8*)(gA + (long long)(it * 32 + rsub) * lda + k0 + kb);
        #pragma unroll
        for (int it = 0; it < BN / 32; ++it)
            rb[it] = *(const us8*)(gB + (long long)(it * 32 + rsub) * ldb + k0 + kb);

        __syncthreads();
        #pragma unroll
        for (int it = 0; it < BM / 32; ++it)
            *(us8*)&sA[(it * 32 + rsub) * BK + kb] = ra[it];
        #pragma unroll
        for (int it = 0; it < BN / 32; ++it)
            *(us8*)&sB[(it * 32 + rsub) * BK + kb] = rb[it];
        __syncthreads();

        #pragma unroll
        for (int kk = 0; kk < BK; kk += 32) {
            const int kro = kk + ((lane >> 4) << 3);
            us8 af[TM], bfr[TN];
            #pragma unroll
            for (int i = 0; i < TM; ++i)
                af[i] = *(const us8*)&sA[(wr * WM + i * 16 + (lane & 15)) * BK + kro];
            #pragma unroll
            for (int j = 0; j < TN; ++j)
                bfr[j] = *(const us8*)&sB[(wc * WN + j * 16 + (lane & 15)) * BK + kro];
            #pragma unroll
            for (int i = 0; i < TM; ++i)
                #pragma unroll
                for (int j = 0; j < TN; ++j)
                    acc[i][j] = mfma16(af[i], bfr[j], acc[i][j]);
        }
    }

    const int quad = lane >> 4;
    const int cn = lane & 15;
    #pragma unroll
    for (int i = 0; i < TM; ++i) {
        #pragma unroll
        for (int j = 0; j < TN; ++j) {
            const int col = n0 + wc * WN + j * 16 + cn;
            #pragma unroll
            for (int r = 0; r < 4; ++r) {
                const int row = m0 + wr * WM + i * 16 + quad * 4 + r;
                const long long idx = (long long)row * ldc + col;
                const float v = acc[i][j][r];
                if constexpr (EPI == 0) ((bfu*)outP)[idx] = f2bf(v);
                else if constexpr (EPI == 1) ((float*)outP)[idx] = resF[idx] + v;
                else ((bfu*)outP)[idx] = f2bf(fmaxf(v, 0.0f));
            }
        }
    }
}

// ---------------------------------------------------------------------------
// Fused cross-attention v6: LDS-FREE flash kernel (m214-class).
// R5 diagnosis: old 3-phase structure saturated the per-CU DS pipe (~4900
// DS cycles/block vs 5650 block cycles: scalar S-stores + softmax bpermutes
// + phase-3 S re-reads). v6 eliminates the S LDS round-trip entirely:
//   - one wave per 32 q-rows, mfma_32x32x16 with SWAPPED operands:
//     P_tile = mfma(A=K, B=Q) -> D[key][q], col=lane&31=q, so each lane owns
//     one q-column; its 16 key-values (rows crow(r,hi)=(r&3)+8*(r>>2)+4*hi)
//     are LANE-LOCAL -> softmax is VALU + 2 shfl_xor(32) per tile.
//   - online flash softmax with defer-max (THR=8, T13): P<=e^8, rescale of O
//     only when the wave-uniform __all check fails (rare).
//   - P repacked to bf16 PV A-frags in-register: 8 v_cvt_pk_bf16_f32 +
//     4 shfl_xor(32) + selects (T12 pattern).
//   - PV: O^T accum via mfma(A=P, B=V^T-frag from v2t, coalesced us8 reads).
// No __shared__, no barriers. Grid (x=bh, y=q/128): XCD = bh%8 pinning kept.
// ---------------------------------------------------------------------------
__global__ __launch_bounds__(256) void xattn(
    const bfu* __restrict__ q2,    // (b, 2048, 1024), head h at col h*64
    const bfu* __restrict__ kv2,   // (b, 1024, 2048): K cols 0-1023
    const bfu* __restrict__ v2t,   // (bh=b*16+h, 64, 1024) = (d, key)
    const float* __restrict__ bias,// (16, 2048, 1024) fp32
    bfu* __restrict__ O)           // (b, 2048, 1024)
{
    const int tid = threadIdx.x, lane = tid & 63, wid = tid >> 6;
    const int l32 = lane & 31, hi = lane >> 5;
    const int bh = blockIdx.x, b = bh >> 4, h = bh & 15;
    const int q0 = blockIdx.y * 128 + wid * 32;

    // Q fragments (persistent): B-frag rows = q = lane&31, k = d = kk*16+hi*8+j
    const bfu* qrow = q2 + (long long)(b * 2048 + q0 + l32) * 1024 + h * 64 + hi * 8;
    const us8 qf0 = *(const us8*)(qrow);
    const us8 qf1 = *(const us8*)(qrow + 16);
    const us8 qf2 = *(const us8*)(qrow + 32);
    const us8 qf3 = *(const us8*)(qrow + 48);

    const bfu* krow  = kv2 + (long long)b * 2097152 + (long long)l32 * 2048 + h * 64 + hi * 8;
    const bfu* vrow0 = v2t + (long long)bh * 65536 + (long long)l32 * 1024 + hi * 8;
    const bfu* vrow1 = vrow0 + 32 * 1024;
    const float* brow = bias + (long long)(h * 2048 + q0 + l32) * 1024 + hi * 4;

    f16v o0 = (f16v)0.0f, o1 = (f16v)0.0f;
    float mrun = -3.0e38f, lrun = 0.0f;

    for (int kt = 0; kt < 32; ++kt) {
        // K frags: A-frag rows = key = kt*32 + lane&31, k = d slice
        const bfu* kp = krow + (long long)kt * 65536;   // 32 rows * 2048
        const us8 kf0 = *(const us8*)(kp);
        const us8 kf1 = *(const us8*)(kp + 16);
        const us8 kf2 = *(const us8*)(kp + 32);
        const us8 kf3 = *(const us8*)(kp + 48);
        f16v p = (f16v)0.0f;
        p = mfma32(kf0, qf0, p);
        p = mfma32(kf1, qf1, p);
        p = mfma32(kf2, qf2, p);
        p = mfma32(kf3, qf3, p);

        // bias for this lane's q-row: keys kt*32 + g*8 + hi*4 + (0..3)
        const float* bp = brow + kt * 32;
        const f4v b0 = *(const f4v*)(bp);
        const f4v b1 = *(const f4v*)(bp + 8);
        const f4v b2 = *(const f4v*)(bp + 16);
        const f4v b3 = *(const f4v*)(bp + 24);
        p[0] += b0[0];  p[1] += b0[1];  p[2] += b0[2];  p[3] += b0[3];
        p[4] += b1[0];  p[5] += b1[1];  p[6] += b1[2];  p[7] += b1[3];
        p[8] += b2[0];  p[9] += b2[1];  p[10] += b2[2]; p[11] += b2[3];
        p[12] += b3[0]; p[13] += b3[1]; p[14] += b3[2]; p[15] += b3[3];

        // tile max (tree) + cross-half merge
        const float ma = fmaxf(fmaxf(p[0], p[1]), fmaxf(p[2], p[3]));
        const float mb = fmaxf(fmaxf(p[4], p[5]), fmaxf(p[6], p[7]));
        const float mc = fmaxf(fmaxf(p[8], p[9]), fmaxf(p[10], p[11]));
        const float md = fmaxf(fmaxf(p[12], p[13]), fmaxf(p[14], p[15]));
        float tmax = fmaxf(fmaxf(ma, mb), fmaxf(mc, md));
        tmax = fmaxf(tmax, __shfl_xor(tmax, 32));

        // defer-max: rescale only when some q's max grew past THR=8
        if (!__all(tmax <= mrun + 8.0f)) {
            const float mnew = fmaxf(mrun, tmax);
            const float alpha = __expf(mrun - mnew);   // first tile: exp(-inf)=0
            lrun *= alpha;
            #pragma unroll
            for (int r = 0; r < 16; ++r) {
                const float ar = __shfl(alpha, (r & 3) + 8 * (r >> 2) + 4 * hi);
                o0[r] *= ar; o1[r] *= ar;
            }
            mrun = mnew;
        }

        #pragma unroll
        for (int r = 0; r < 16; ++r) p[r] = __expf(p[r] - mrun);

        const float sa = (p[0] + p[1]) + (p[2] + p[3]);
        const float sb = (p[4] + p[5]) + (p[6] + p[7]);
        const float sc = (p[8] + p[9]) + (p[10] + p[11]);
        const float sd = (p[12] + p[13]) + (p[14] + p[15]);
        float tsum = (sa + sb) + (sc + sd);
        tsum += __shfl_xor(tsum, 32);
        lrun += tsum;

        // pack P -> bf16 PV A-frags (keys made contiguous via half-swap)
        const unsigned A0 = cvtpk(p[0], p[1]),   A1 = cvtpk(p[2], p[3]);
        const unsigned B0 = cvtpk(p[4], p[5]),   B1 = cvtpk(p[6], p[7]);
        const unsigned C0 = cvtpk(p[8], p[9]),   C1 = cvtpk(p[10], p[11]);
        const unsigned D0 = cvtpk(p[12], p[13]), D1 = cvtpk(p[14], p[15]);
        const unsigned s0 = (unsigned)__shfl_xor((int)(hi ? A0 : B0), 32);
        const unsigned s1 = (unsigned)__shfl_xor((int)(hi ? A1 : B1), 32);
        const unsigned s2 = (unsigned)__shfl_xor((int)(hi ? C0 : D0), 32);
        const unsigned s3 = (unsigned)__shfl_xor((int)(hi ? C1 : D1), 32);
        const us8 F0 = mkfrag(hi ? s0 : A0, hi ? s1 : A1, hi ? B0 : s0, hi ? B1 : s1);
        const us8 F1 = mkfrag(hi ? s2 : C0, hi ? s3 : C1, hi ? D0 : s2, hi ? D1 : s3);

        // PV: B-frag rows = d = lane&31 (+32 for o1), k = key = hi*8+j
        const bfu* vp0 = vrow0 + kt * 32;
        const bfu* vp1 = vrow1 + kt * 32;
        o0 = mfma32(F0, *(const us8*)(vp0), o0);
        o0 = mfma32(F1, *(const us8*)(vp0 + 16), o0);
        o1 = mfma32(F0, *(const us8*)(vp1), o1);
        o1 = mfma32(F1, *(const us8*)(vp1 + 16), o1);
    }

    // epilogue: O rows are q = crow(r,hi); fetch 1/l per row via shfl
    const float linv = 1.0f / lrun;
    bfu* ob = O + (long long)(b * 2048 + q0) * 1024 + h * 64 + l32;
    #pragma unroll
    for (int r = 0; r < 16; ++r) {
        const int qr = (r & 3) + 8 * (r >> 2) + 4 * hi;
        const float li = __shfl(linv, qr);
        ob[(long long)qr * 1024]      = f2bf(o0[r] * li);
        ob[(long long)qr * 1024 + 32] = f2bf(o1[r] * li);
    }
}

// ---------------------------------------------------------------------------
// fp32 -> bf16 elementwise (4 per thread)
// ---------------------------------------------------------------------------
__global__ __launch_bounds__(256) void cvt_f2b(
    const float* __restrict__ in, bfu* __restrict__ out)
{
    const long long i = ((long long)blockIdx.x * 256 + threadIdx.x) * 4;
    f4v v = *(const f4v*)(in + i);
    us4 o;
    #pragma unroll
    for (int k = 0; k < 4; ++k) o[k] = f2bf(v[k]);
    *(us4*)(out + i) = o;
}

// ---------------------------------------------------------------------------
// Transposes. Weight transposes read fp32, write bf16.
// ---------------------------------------------------------------------------
__global__ __launch_bounds__(256) void transpose_plain(
    const float* __restrict__ in, bfu* __restrict__ out, int R, int C)
{
    __shared__ bfu t[32][33];
    const int r0 = blockIdx.y * 32, c0 = blockIdx.x * 32;
    const int tx = threadIdx.x, ty = threadIdx.y;
    #pragma unroll
    for (int i = 0; i < 32; i += 8)
        t[ty + i][tx] = f2bf(in[(long long)(r0 + ty + i) * C + c0 + tx]);
    __syncthreads();
    #pragma unroll
    for (int i = 0; i < 32; i += 8)
        out[(long long)(c0 + ty + i) * R + r0 + tx] = t[tx][ty + i];
}

__global__ __launch_bounds__(256) void transpose_w8(
    const float* p0, const float* p1, const float* p2, const float* p3,
    const float* p4, const float* p5, const float* p6, const float* p7,
    bfu* __restrict__ out)
{
    __shared__ bfu t[32][33];
    const float* srcs[8] = {p0, p1, p2, p3, p4, p5, p6, p7};
    const int zz = blockIdx.z;
    const float* in = srcs[zz];
    bfu* o = out + (long long)zz * 1048576;
    const int r0 = blockIdx.y * 32, c0 = blockIdx.x * 32;
    const int tx = threadIdx.x, ty = threadIdx.y;
    #pragma unroll
    for (int i = 0; i < 32; i += 8)
        t[ty + i][tx] = f2bf(in[(long long)(r0 + ty + i) * 1024 + c0 + tx]);
    __syncthreads();
    #pragma unroll
    for (int i = 0; i < 32; i += 8)
        o[(long long)(c0 + ty + i) * 1024 + r0 + tx] = t[tx][ty + i];
}

// kv2 (b, 1024 keys, 2048) V half (cols 1024+h*64 .. +64) -> v2t (bh, 64, 1024)
__global__ __launch_bounds__(256) void transpose_v2(
    const bfu* __restrict__ kv2, bfu* __restrict__ v2t)
{
    __shared__ bfu t[32][33];
    const int z = blockIdx.z, b = z >> 4, h = z & 15;
    const bfu* in = kv2 + (long long)b * 2097152 + 1024 + h * 64;  // row stride 2048
    bfu* o = v2t + (long long)z * 65536;
    const int c0 = blockIdx.x * 32, r0 = blockIdx.y * 32;
    const int tx = threadIdx.x, ty = threadIdx.y;
    #pragma unroll
    for (int i = 0; i < 32; i += 8)
        t[ty + i][tx] = in[(long long)(r0 + ty + i) * 2048 + c0 + tx];
    __syncthreads();
    #pragma unroll
    for (int i = 0; i < 32; i += 8)
        o[(long long)(c0 + ty + i) * 1024 + r0 + tx] = t[tx][ty + i];
}

// ---------------------------------------------------------------------------
// RMSNorm family (fp32 in, bf16 normed out; 256 thr x 4 elems per 1024 row)
// ---------------------------------------------------------------------------
__device__ __forceinline__ float blockSum4(float v, float* red) {
    const int lane = threadIdx.x & 63, wid = threadIdx.x >> 6;
    #pragma unroll
    for (int o = 32; o; o >>= 1) v += __shfl_xor(v, o);
    if (lane == 0) red[wid] = v;
    __syncthreads();
    return red[0] + red[1] + red[2] + red[3];
}

__global__ __launch_bounds__(256) void rmsnorm_f32k(
    const float* __restrict__ X, const float* __restrict__ w, bfu* __restrict__ O)
{
    __shared__ float red[4];
    const long long row = blockIdx.x;
    const int tid = threadIdx.x;
    f4v xv = *(const f4v*)(X + row * 1024 + tid * 4);
    float ss = 0.f;
    #pragma unroll
    for (int i = 0; i < 4; ++i) ss += xv[i] * xv[i];
    ss = blockSum4(ss, red);
    const float sc = rsqrtf(ss * (1.0f / 1024.0f) + 1e-6f);
    f4v wv = *(const f4v*)(w + tid * 4);
    us4 o4;
    #pragma unroll
    for (int i = 0; i < 4; ++i) o4[i] = f2bf(xv[i] * sc * wv[i]);
    *(us4*)(O + row * 1024 + tid * 4) = o4;
}

// x1 = x + attn[b] (fp32); write x1 (fp32) and rmsnorm(x1)*w (bf16)
__global__ __launch_bounds__(256) void add_bcast_rmsnorm(
    const float* __restrict__ X, const float* __restrict__ attn,
    const float* __restrict__ w, float* __restrict__ X1, bfu* __restrict__ O)
{
    __shared__ float red[4];
    const long long row = blockIdx.x;
    const int b = (int)(row >> 11);
    const int tid = threadIdx.x;
    f4v xv = *(const f4v*)(X + row * 1024 + tid * 4);
    f4v av = *(const f4v*)(attn + b * 1024 + tid * 4);
    f4v v;
    float ss = 0.f;
    #pragma unroll
    for (int i = 0; i < 4; ++i) { v[i] = xv[i] + av[i]; ss += v[i] * v[i]; }
    *(f4v*)(X1 + row * 1024 + tid * 4) = v;
    ss = blockSum4(ss, red);
    const float sc = rsqrtf(ss * (1.0f / 1024.0f) + 1e-6f);
    f4v wv = *(const f4v*)(w + tid * 4);
    us4 o4;
    #pragma unroll
    for (int i = 0; i < 4; ++i) o4[i] = f2bf(v[i] * sc * wv[i]);
    *(us4*)(O + row * 1024 + tid * 4) = o4;
}

// ---------------------------------------------------------------------------
// small dense: C[b][n] = dot(A[aBase + b*aStride + :K], Bt[n*K + :K])
// ---------------------------------------------------------------------------
template<int OUTF>
__global__ __launch_bounds__(256) void vecmat(
    const bfu* __restrict__ A, const bfu* __restrict__ Bt, void* __restrict__ out,
    int K, int N, long long aStride, long long aBase)
{
    __shared__ float sa[1024];
    const int tid = threadIdx.x;
    const int b = blockIdx.y;
    const bfu* ar = A + aBase + (long long)b * aStride;
    for (int k = tid; k < K; k += 256) sa[k] = bf2f(ar[k]);
    __syncthreads();
    const int n = blockIdx.x * 256 + tid;
    if (n < N) {
        const bfu* wr = Bt + (long long)n * K;
        float s = 0.f;
        for (int k = 0; k < K; k += 8) {
            us8 wv = *(const us8*)(wr + k);
            #pragma unroll
            for (int j = 0; j < 8; ++j) s += sa[k + j] * bf2f(wv[j]);
        }
        if constexpr (OUTF) ((float*)out)[(long long)b * N + n] = s;
        else ((bfu*)out)[(long long)b * N + n] = f2bf(s);
    }
}

// ---------------------------------------------------------------------------
// decode self-attention: one block per (b,h); q len = 1, 2048 keys, d=64.
// KV interleaved: row stride 2048, K at cols 0-1023, V at cols 1024-2047.
// ---------------------------------------------------------------------------
__global__ __launch_bounds__(256) void decode_attn(
    const bfu* __restrict__ qs, const bfu* __restrict__ KV,
    const float* __restrict__ bias, bfu* __restrict__ osmall)
{
    const int bh = blockIdx.x, b = bh >> 4, h = bh & 15;
    const int tid = threadIdx.x, lane = tid & 63, wid = tid >> 6;
    __shared__ float sq[64];
    __shared__ float sc[2048];
    __shared__ float red[4];
    __shared__ float po[4][64];
    if (tid < 64) sq[tid] = bf2f(qs[b * 1024 + h * 64 + tid]);
    __syncthreads();

    const bfu* Kb = KV + (long long)b * 2048 * 2048 + h * 64;
    float lmax = -1e30f;
    for (int k = tid; k < 2048; k += 256) {
        const us8* kr = (const us8*)(Kb + (long long)k * 2048);
        float s = 0.f;
        #pragma unroll
        for (int j = 0; j < 8; ++j) {
            us8 kv = kr[j];
            #pragma unroll
            for (int t = 0; t < 8; ++t) s += sq[j * 8 + t] * bf2f(kv[t]);
        }
        s += bias[h * 2048 + k];
        sc[k] = s;
        lmax = fmaxf(lmax, s);
    }
    #pragma unroll
    for (int o = 32; o; o >>= 1) lmax = fmaxf(lmax, __shfl_xor(lmax, o));
    if (lane == 0) red[wid] = lmax;
    __syncthreads();
    const float m = fmaxf(fmaxf(red[0], red[1]), fmaxf(red[2], red[3]));
    __syncthreads();

    float lsum = 0.f;
    for (int k = tid; k < 2048; k += 256) {
        const float e = __expf(sc[k] - m);
        sc[k] = e; lsum += e;
    }
    #pragma unroll
    for (int o = 32; o; o >>= 1) lsum += __shfl_xor(lsum, o);
    if (lane == 0) red[wid] = lsum;
    __syncthreads();
    const float S = red[0] + red[1] + red[2] + red[3];

    const bfu* Vb = KV + (long long)b * 2048 * 2048 + 1024 + h * 64;
    const int d = tid & 63, ks = tid >> 6;
    float a = 0.f;
    for (int k = ks * 512; k < ks * 512 + 512; ++k)
        a += sc[k] * bf2f(Vb[(long long)k * 2048 + d]);
    po[ks][d] = a;
    __syncthreads();
    if (tid < 64) {
        const float r = (po[0][tid] + po[1][tid] + po[2][tid] + po[3][tid]) / S;
        osmall[b * 1024 + h * 64 + tid] = f2bf(r);
    }
}

// ---------------------------------------------------------------------------
extern "C" void kernel_launch(void* const* d_in, const int* in_sizes, int n_in,
                              void* d_out, int out_size, void* d_ws, size_t ws_size,
                              hipStream_t stream) {
    (void)in_sizes; (void)n_in; (void)out_size; (void)ws_size;
    const float* x     = (const float*)d_in[0];
    const float* enc   = (const float*)d_in[1];
    const float* sbias = (const float*)d_in[2];
    const float* cbias = (const float*)d_in[3];
    const float* wq_s  = (const float*)d_in[4];
    const float* wk_s  = (const float*)d_in[5];
    const float* wv_s  = (const float*)d_in[6];
    const float* wo_s  = (const float*)d_in[7];
    const float* wq_c  = (const float*)d_in[8];
    const float* wk_c  = (const float*)d_in[9];
    const float* wv_c  = (const float*)d_in[10];
    const float* wo_c  = (const float*)d_in[11];
    const float* ff1   = (const float*)d_in[12];
    const float* ff2   = (const float*)d_in[13];
    const float* n1w   = (const float*)d_in[14];
    const float* n2w   = (const float*)d_in[15];
    const float* n3w   = (const float*)d_in[16];
    float* out = (float*)d_out;

    char* ws = (char*)d_ws;
    size_t off = 0;
    auto alloc = [&](size_t bytes) -> void* {
        void* p = (void*)(ws + off);
        off += (bytes + 255) & ~(size_t)255;
        return p;
    };
    bfu*   normed = (bfu*)alloc((size_t)8192 * 1024 * 2);   // [0:16)  normed1/2/3
    bfu*   kvs    = (bfu*)alloc((size_t)8192 * 2048 * 2);   // [16:48) self KV interleaved
    bfu*   obuf   = (bfu*)alloc((size_t)8192 * 1024 * 2);   // [48:64) cross-attn O
    bfu*   v2t    = (bfu*)alloc((size_t)4096 * 1024 * 2);   // [64:72)
    bfu*   encb   = (bfu*)alloc((size_t)4096 * 1024 * 2);   // [72:80)
    float* x1f    = (float*)alloc((size_t)8192 * 1024 * 4); // [80:112) fp32 residual
    bfu*   wT     = (bfu*)alloc((size_t)8 * 1048576 * 2);   // [112:128) transposed weights
    bfu*   ff1T   = (bfu*)alloc((size_t)4096 * 1024 * 2);   // [128:136)
    bfu*   ff2T   = (bfu*)alloc((size_t)4096 * 1024 * 2);   // [136:144)
    bfu*   qsb    = (bfu*)alloc(4 * 1024 * 2);
    bfu*   osm    = (bfu*)alloc(4 * 1024 * 2);
    float* attnv  = (float*)alloc(4 * 1024 * 4);
    // Aliases (liveness-checked):
    bfu*   q2b = kvs;                        // cross Q (kvs dead after decode)
    bfu*   kv2 = kvs + (size_t)8192 * 1024;  // cross KV interleaved
    bfu*   H1  = kvs;                        // MLP hidden: 64 MB dead region

    const dim3 tb32(32, 8);

    // input/weight precasts
    cvt_f2b<<<dim3(4096), 256, 0, stream>>>(enc, encb);
    transpose_w8<<<dim3(32, 32, 8), tb32, 0, stream>>>(
        wq_s, wk_s, wv_s, wo_s, wq_c, wk_c, wv_c, wo_c, wT);
    transpose_plain<<<dim3(128, 32, 1), tb32, 0, stream>>>(ff1, ff1T, 1024, 4096);
    transpose_plain<<<dim3(32, 128, 1), tb32, 0, stream>>>(ff2, ff2T, 4096, 1024);

    // norm1
    rmsnorm_f32k<<<dim3(8192), 256, 0, stream>>>(x, n1w, normed);

    // self-attn K|V fused projection: normed @ [wk_s|wv_s] -> kvs (ldc 2048)
    gemm_bt<128, 128, 0><<<dim3(16, 64), 256, 0, stream>>>(
        normed, wT + 1 * 1048576, nullptr, kvs, 1024, 1024, 1024, 2048);
    // q = last row per batch
    vecmat<0><<<dim3(4, 4), 256, 0, stream>>>(normed, wT + 0 * 1048576, qsb,
        1024, 1024, (long long)2048 * 1024, (long long)2047 * 1024);
    decode_attn<<<dim3(64), 256, 0, stream>>>(qsb, kvs, sbias, osm);
    vecmat<1><<<dim3(4, 4), 256, 0, stream>>>(osm, wT + 3 * 1048576, attnv,
        1024, 1024, 1024, 0);
    add_bcast_rmsnorm<<<dim3(8192), 256, 0, stream>>>(x, attnv, n2w, x1f, normed);

    // cross-attn projections (kvs dead now; q2b/kv2 alias it)
    gemm_bt<128, 64, 0><<<dim3(16, 64), 256, 0, stream>>>(
        normed, wT + 4 * 1048576, nullptr, q2b, 1024, 1024, 1024, 1024);
    gemm_bt<128, 64, 0><<<dim3(32, 32), 256, 0, stream>>>(
        encb, wT + 5 * 1048576, nullptr, kv2, 1024, 1024, 1024, 2048);
    transpose_v2<<<dim3(2, 32, 64), tb32, 0, stream>>>(kv2, v2t);

    // fused cross-attention v6 (LDS-free flash; grid x=bh keeps XCD pinning)
    xattn<<<dim3(64, 16), 256, 0, stream>>>(q2b, kv2, v2t, cbias, obuf);

    // wo_c with residual add: x2 = x1 + O@woT (fp32, in place over x1f)
    gemm_bt<128, 64, 1><<<dim3(16, 64), 256, 0, stream>>>(
        obuf, wT + 7 * 1048576, x1f, x1f, 1024, 1024, 1024, 1024);

    // norm3 + MLP, single full-M launches (H1 = 64 MB dead region)
    rmsnorm_f32k<<<dim3(8192), 256, 0, stream>>>(x1f, n3w, normed);
    gemm_bt<128, 128, 2><<<dim3(32, 64), 256, 0, stream>>>(
        normed, ff1T, nullptr, H1, 1024, 1024, 1024, 4096);
    gemm_bt<128, 64, 1><<<dim3(16, 64), 256, 0, stream>>>(
        H1, ff2T, x1f, out, 4096, 4096, 4096, 1024);
}